// Round 1
// baseline (50.976 us; speedup 1.0000x reference)
//
#include <hip/hip_runtime.h>

#define FS 32
#define NS 30            // num_sample = filter_size - 2
#define FDIM 256
#define ROWS_PER_BLOCK 4 // one wave (64 lanes) per output row b

__global__ __launch_bounds__(256) void stc_gather_kernel(
    const float* __restrict__ feat,     // [100000, 256]
    const int*   __restrict__ nidx,     // [B, 30]
    const float* __restrict__ weight,   // [32]
    const float* __restrict__ avgw,     // [32]
    const float* __restrict__ U,        // [32, 32] row-major U[f][g]
    float* __restrict__ out,            // [B, 256]
    int B)
{
    __shared__ float t_sh[FS];                    // w[g] * sum_f U[f][g]*avg[f]
    __shared__ float c_sh[FS];                    // c[f'] = sum_g U[f'][g]*t[g]
    __shared__ int   idx_sh[ROWS_PER_BLOCK * NS];

    const int tid = threadIdx.x;
    const int b0  = blockIdx.x * ROWS_PER_BLOCK;

    // t[g] = weight[g] * sum_f U[f][g] * avg[f]
    if (tid < FS) {
        float t = 0.f;
        #pragma unroll
        for (int f = 0; f < FS; ++f) t += U[f * FS + tid] * avgw[f];
        t_sh[tid] = t * weight[tid];
    }
    // stage this block's neighbor indices
    if (tid < ROWS_PER_BLOCK * NS) {
        int r = tid / NS, s = tid - r * NS;
        int b = b0 + r;
        idx_sh[tid] = (b < B) ? nidx[b * NS + s] : 0;
    }
    __syncthreads();
    // c[f'] = sum_g U[f'][g] * t[g]
    if (tid < FS) {
        float c = 0.f;
        #pragma unroll
        for (int g = 0; g < FS; ++g) c += U[tid * FS + g] * t_sh[g];
        c_sh[tid] = c;
    }
    __syncthreads();

    const int wave = tid >> 6;
    const int lane = tid & 63;
    const int b = b0 + wave;
    if (b >= B) return;

    const int* myidx = &idx_sh[wave * NS];
    float4 acc = make_float4(0.f, 0.f, 0.f, 0.f);

    #pragma unroll 6
    for (int s = 0; s < NS; ++s) {
        const int row = myidx[s];
        const float4 v = *((const float4*)(feat + (long long)row * FDIM) + lane);
        const float cs = c_sh[s + 1];   // slot 0 (center) and slot 31 are zero-padded
        acc.x += v.x * cs;
        acc.y += v.y * cs;
        acc.z += v.z * cs;
        acc.w += v.w * cs;
    }

    *((float4*)(out + (long long)b * FDIM) + lane) = acc;
}

extern "C" void kernel_launch(void* const* d_in, const int* in_sizes, int n_in,
                              void* d_out, int out_size, void* d_ws, size_t ws_size,
                              hipStream_t stream) {
    const float* feat   = (const float*)d_in[0];
    const int*   nidx   = (const int*)d_in[1];
    const float* weight = (const float*)d_in[2];
    const float* avgw   = (const float*)d_in[3];
    const float* U      = (const float*)d_in[4];
    float* out = (float*)d_out;

    const int B = in_sizes[1] / NS;   // 10000
    const int grid = (B + ROWS_PER_BLOCK - 1) / ROWS_PER_BLOCK;

    stc_gather_kernel<<<grid, 256, 0, stream>>>(feat, nidx, weight, avgw, U, out, B);
}

// Round 2
// 50.253 us; speedup vs baseline: 1.0144x; 1.0144x over previous
//
#include <hip/hip_runtime.h>

#define FS 32
#define NS 30            // num_sample = filter_size - 2
#define FDIM 256
#define RPB 4            // one wave (64 lanes) per output row b

__global__ __launch_bounds__(256) void stc_gather_sorted(
    const float* __restrict__ feat,     // [100000, 256]
    const int*   __restrict__ nidx,     // [B, 30]
    const float* __restrict__ weight,   // [32]
    const float* __restrict__ avgw,     // [32]
    const float* __restrict__ U,        // [32, 32] row-major
    float* __restrict__ out,            // [B, 256]
    int B)
{
    __shared__ float t_sh[FS];
    __shared__ float c_sh[FS];
    __shared__ int   idx_sh[RPB * NS];
    __shared__ int   sidx_sh[RPB * NS];   // idx sorted ascending per wave
    __shared__ float scoef_sh[RPB * NS];  // coefficient permuted alongside

    const int tid = threadIdx.x;
    const int b0  = blockIdx.x * RPB;

    // t[g] = weight[g] * sum_f U[f][g] * avg[f]
    if (tid < FS) {
        float t = 0.f;
        #pragma unroll
        for (int f = 0; f < FS; ++f) t += U[f * FS + tid] * avgw[f];
        t_sh[tid] = t * weight[tid];
    }
    // stage this block's neighbor indices
    if (tid < RPB * NS) {
        int r = tid / NS, s = tid - r * NS;
        int b = b0 + r;
        idx_sh[tid] = (b < B) ? nidx[b * NS + s] : 0;
    }
    __syncthreads();
    // c[f'] = sum_g U[f'][g] * t[g]
    if (tid < FS) {
        float c = 0.f;
        #pragma unroll
        for (int g = 0; g < FS; ++g) c += U[tid * FS + g] * t_sh[g];
        c_sh[tid] = c;
    }
    __syncthreads();

    // Per-wave rank-sort of the 30 (idx, coef) pairs by idx ascending.
    // All waves then walk the feat table in ascending address order ->
    // quasi-streaming HBM pattern + temporal clustering of duplicate rows.
    {
        const int wave = tid >> 6, lane = tid & 63;
        if (lane < NS) {
            const int base = wave * NS;
            const int key  = idx_sh[base + lane];
            int rank = 0;
            #pragma unroll
            for (int j = 0; j < NS; ++j) {
                const int kj = idx_sh[base + j];
                rank += (kj < key) || (kj == key && j < lane);
            }
            sidx_sh[base + rank]  = key;
            scoef_sh[base + rank] = c_sh[lane + 1]; // slots 0 and 31 are zero-padded
        }
    }
    __syncthreads();

    const int wave = tid >> 6;
    const int lane = tid & 63;
    const int b = b0 + wave;
    if (b >= B) return;

    const int*   myidx = &sidx_sh[wave * NS];
    const float* myc   = &scoef_sh[wave * NS];
    float4 acc = make_float4(0.f, 0.f, 0.f, 0.f);

    #pragma unroll 6
    for (int s = 0; s < NS; ++s) {
        const int   row = myidx[s];
        const float4 v  = *((const float4*)(feat + (long long)row * FDIM) + lane);
        const float cs  = myc[s];
        acc.x += v.x * cs;
        acc.y += v.y * cs;
        acc.z += v.z * cs;
        acc.w += v.w * cs;
    }

    *((float4*)(out + (long long)b * FDIM) + lane) = acc;
}

extern "C" void kernel_launch(void* const* d_in, const int* in_sizes, int n_in,
                              void* d_out, int out_size, void* d_ws, size_t ws_size,
                              hipStream_t stream) {
    const float* feat   = (const float*)d_in[0];
    const int*   nidx   = (const int*)d_in[1];
    const float* weight = (const float*)d_in[2];
    const float* avgw   = (const float*)d_in[3];
    const float* U      = (const float*)d_in[4];
    float* out = (float*)d_out;

    const int B = in_sizes[1] / NS;   // 10000
    const int grid = (B + RPB - 1) / RPB;

    stc_gather_sorted<<<grid, 256, 0, stream>>>(feat, nidx, weight, avgw, U, out, B);
}